// Round 5
// baseline (722.466 us; speedup 1.0000x reference)
//
#include <hip/hip_runtime.h>

// ---------------------------------------------------------------------------
// 2-layer GCN, pull aggregation via padded CSR (capacity 96 slots/node).
// Round 5: fill (latency-bound, machine-idle) fused with GEMM1 (compute-bound)
// in one heterogeneous-block kernel. dinv scaling moved from GEMM epilogue
// into gather (h stored unnormalized in bf16), removing the fill->gemm dep.
// out[d] = relu( dinv[d]*( dinv[d]*h[d] + sum_s dinv[s]*h[s] ) + b )
// ---------------------------------------------------------------------------

#define CAP 96

__device__ __forceinline__ unsigned short f2bf(float f) {
    unsigned int u = __float_as_uint(f);
    u += 0x7fffu + ((u >> 16) & 1u);          // round-to-nearest-even
    return (unsigned short)(u >> 16);
}
__device__ __forceinline__ float bflo(unsigned int u) { return __uint_as_float(u << 16); }
__device__ __forceinline__ float bfhi(unsigned int u) { return __uint_as_float(u & 0xffff0000u); }

__global__ __launch_bounds__(256) void k_cnt_init(unsigned int* cnt, int n) {
    int v = blockIdx.x * 256 + threadIdx.x;
    if (v < n) cnt[v] = 0u;
}

__global__ __launch_bounds__(256) void k_dinv(const unsigned int* __restrict__ cnt,
                                              float* __restrict__ dinv, int n) {
    int v = blockIdx.x * 256 + threadIdx.x;
    if (v < n) dinv[v] = rsqrtf((float)(cnt[v] + 1u));
}

// Heterogeneous kernel:
//   blockIdx.x <  nbF : padded-CSR fill, 8 edges/thread (latency-bound)
//   blockIdx.x >= nbF : H[M,128] = bf16(A[M,K] @ B[K,128]), 64x128 tile
// Layer-2 GEMM reuses this kernel with nbF = 0.
__global__ __launch_bounds__(256) void k_fill_gemm(
        const int* __restrict__ src, const int* __restrict__ dst,
        unsigned int* __restrict__ cnt, int* __restrict__ csr, int E, int nbF,
        const float* __restrict__ A, const float* __restrict__ B,
        unsigned short* __restrict__ H, int M, int K) {
    __shared__ float As[16][64];    // As[k][m]
    __shared__ float Bs[16][128];   // Bs[k][n]
    const int tid = threadIdx.x;

    if ((int)blockIdx.x < nbF) {
        // ---------------- fill path ----------------
        const int base = (blockIdx.x * 256 + tid) * 8;
        if (base >= E) return;
        if (base + 7 < E) {
            const int4 s0 = *reinterpret_cast<const int4*>(src + base);
            const int4 s1 = *reinterpret_cast<const int4*>(src + base + 4);
            const int4 d0 = *reinterpret_cast<const int4*>(dst + base);
            const int4 d1 = *reinterpret_cast<const int4*>(dst + base + 4);
            const unsigned int p0 = atomicAdd(&cnt[d0.x], 1u);
            const unsigned int p1 = atomicAdd(&cnt[d0.y], 1u);
            const unsigned int p2 = atomicAdd(&cnt[d0.z], 1u);
            const unsigned int p3 = atomicAdd(&cnt[d0.w], 1u);
            const unsigned int p4 = atomicAdd(&cnt[d1.x], 1u);
            const unsigned int p5 = atomicAdd(&cnt[d1.y], 1u);
            const unsigned int p6 = atomicAdd(&cnt[d1.z], 1u);
            const unsigned int p7 = atomicAdd(&cnt[d1.w], 1u);
            csr[(size_t)d0.x * CAP + p0] = s0.x;
            csr[(size_t)d0.y * CAP + p1] = s0.y;
            csr[(size_t)d0.z * CAP + p2] = s0.z;
            csr[(size_t)d0.w * CAP + p3] = s0.w;
            csr[(size_t)d1.x * CAP + p4] = s1.x;
            csr[(size_t)d1.y * CAP + p5] = s1.y;
            csr[(size_t)d1.z * CAP + p6] = s1.z;
            csr[(size_t)d1.w * CAP + p7] = s1.w;
        } else {
            for (int e = base; e < E; ++e) {
                const int s = src[e], d = dst[e];
                const unsigned int p = atomicAdd(&cnt[d], 1u);
                csr[(size_t)d * CAP + p] = s;
            }
        }
        return;
    }

    // ---------------- gemm path (64x128 tile, 4x8 per thread) ----------------
    const int row0 = (blockIdx.x - nbF) * 64;
    const int ty = tid >> 4;            // 0..15  -> rows ty*4..ty*4+3
    const int tx = tid & 15;            // 0..15  -> cols tx*8..tx*8+7
    const int a_row = tid >> 2;         // 0..63
    const int a_k4  = (tid & 3) * 4;    // 0,4,8,12
    const int b_k   = tid >> 4;         // 0..15
    const int b_c8  = (tid & 15) * 8;   // 0..120

    float acc[4][8] = {};

    for (int kt = 0; kt < K; kt += 16) {
        float4 av = make_float4(0.f, 0.f, 0.f, 0.f);
        const int ar = row0 + a_row;
        if (ar < M)
            av = *reinterpret_cast<const float4*>(A + (size_t)ar * K + kt + a_k4);
        As[a_k4 + 0][a_row] = av.x;
        As[a_k4 + 1][a_row] = av.y;
        As[a_k4 + 2][a_row] = av.z;
        As[a_k4 + 3][a_row] = av.w;

        const float* bp = B + (size_t)(kt + b_k) * 128 + b_c8;
        *reinterpret_cast<float4*>(&Bs[b_k][b_c8])     = *reinterpret_cast<const float4*>(bp);
        *reinterpret_cast<float4*>(&Bs[b_k][b_c8 + 4]) = *reinterpret_cast<const float4*>(bp + 4);

        __syncthreads();
#pragma unroll
        for (int k = 0; k < 16; ++k) {
            const float4 a4 = *reinterpret_cast<const float4*>(&As[k][ty * 4]);
            const float4 b0 = *reinterpret_cast<const float4*>(&Bs[k][tx * 8]);
            const float4 b1 = *reinterpret_cast<const float4*>(&Bs[k][tx * 8 + 4]);
            const float ar4[4] = {a4.x, a4.y, a4.z, a4.w};
            const float br8[8] = {b0.x, b0.y, b0.z, b0.w, b1.x, b1.y, b1.z, b1.w};
#pragma unroll
            for (int i = 0; i < 4; ++i)
#pragma unroll
                for (int j = 0; j < 8; ++j)
                    acc[i][j] = fmaf(ar4[i], br8[j], acc[i][j]);
        }
        __syncthreads();
    }

#pragma unroll
    for (int i = 0; i < 4; ++i) {
        const int r = row0 + ty * 4 + i;
        if (r >= M) continue;
        ushort4 o0, o1;
        o0.x = f2bf(acc[i][0]); o0.y = f2bf(acc[i][1]);
        o0.z = f2bf(acc[i][2]); o0.w = f2bf(acc[i][3]);
        o1.x = f2bf(acc[i][4]); o1.y = f2bf(acc[i][5]);
        o1.z = f2bf(acc[i][6]); o1.w = f2bf(acc[i][7]);
        unsigned short* hp = H + (size_t)r * 128 + tx * 8;
        *reinterpret_cast<ushort4*>(hp)     = o0;
        *reinterpret_cast<ushort4*>(hp + 4) = o1;
    }
}

// Pull aggregation over bf16 h rows (unnormalized); per-source dinv applied
// in the inner fma. Fused self-loop + final dinv + bias + ReLU.
// 16 nodes per 256-thread block; 16 lanes per node; 8 cols (16B) per lane.
__global__ __launch_bounds__(256) void k_gather(const unsigned int* __restrict__ cnt,
                                                const int* __restrict__ csr,
                                                const float* __restrict__ dinv,
                                                const unsigned short* __restrict__ H,
                                                const float* __restrict__ bias,
                                                float* __restrict__ outp, int N) {
    const int t = threadIdx.x;
    const int node = blockIdx.x * 16 + (t >> 4);
    if (node >= N) return;
    const int lane = t & 15;
    const int c8 = lane * 8;

    const float dv = dinv[node];
    const uint4 hv = *reinterpret_cast<const uint4*>(H + (size_t)node * 128 + c8);
    float acc0 = dv * bflo(hv.x), acc1 = dv * bfhi(hv.x);
    float acc2 = dv * bflo(hv.y), acc3 = dv * bfhi(hv.y);
    float acc4 = dv * bflo(hv.z), acc5 = dv * bfhi(hv.z);
    float acc6 = dv * bflo(hv.w), acc7 = dv * bfhi(hv.w);

    const int beg = node * CAP;
    const int end = beg + (int)cnt[node];
    for (int r = beg; r < end; r += 16) {
        const int cntc = min(16, end - r);
        int sv = (lane < cntc) ? csr[r + lane] : 0;
        for (int j = 0; j < cntc; ++j) {
            const int s = __shfl(sv, j, 16);
            const float w = dinv[s];
            const uint4 x = *reinterpret_cast<const uint4*>(H + (size_t)s * 128 + c8);
            acc0 = fmaf(w, bflo(x.x), acc0); acc1 = fmaf(w, bfhi(x.x), acc1);
            acc2 = fmaf(w, bflo(x.y), acc2); acc3 = fmaf(w, bfhi(x.y), acc3);
            acc4 = fmaf(w, bflo(x.z), acc4); acc5 = fmaf(w, bfhi(x.z), acc5);
            acc6 = fmaf(w, bflo(x.w), acc6); acc7 = fmaf(w, bfhi(x.w), acc7);
        }
    }

    const float4 b0 = *reinterpret_cast<const float4*>(bias + c8);
    const float4 b1 = *reinterpret_cast<const float4*>(bias + c8 + 4);
    float4 o0, o1;
    o0.x = fmaxf(fmaf(acc0, dv, b0.x), 0.f);
    o0.y = fmaxf(fmaf(acc1, dv, b0.y), 0.f);
    o0.z = fmaxf(fmaf(acc2, dv, b0.z), 0.f);
    o0.w = fmaxf(fmaf(acc3, dv, b0.w), 0.f);
    o1.x = fmaxf(fmaf(acc4, dv, b1.x), 0.f);
    o1.y = fmaxf(fmaf(acc5, dv, b1.y), 0.f);
    o1.z = fmaxf(fmaf(acc6, dv, b1.z), 0.f);
    o1.w = fmaxf(fmaf(acc7, dv, b1.w), 0.f);
    float* op = outp + (size_t)node * 128 + c8;
    *reinterpret_cast<float4*>(op)     = o0;
    *reinterpret_cast<float4*>(op + 4) = o1;
}

extern "C" void kernel_launch(void* const* d_in, const int* in_sizes, int n_in,
                              void* d_out, int out_size, void* d_ws, size_t ws_size,
                              hipStream_t stream) {
    const float* x  = (const float*)d_in[0];
    const int*   ei = (const int*)d_in[1];
    const float* W1 = (const float*)d_in[3];
    const float* b1 = (const float*)d_in[4];
    const float* W2 = (const float*)d_in[5];
    const float* b2 = (const float*)d_in[6];
    float* out = (float*)d_out;

    const int N = in_sizes[0] / 400;
    const int E = in_sizes[1] / 2;
    const int* src = ei;
    const int* dst = ei + E;

    char* ws = (char*)d_ws;
    size_t off = 0;
    auto alloc = [&](size_t bytes) {
        void* p = ws + off;
        off = (off + bytes + 255) & ~(size_t)255;
        return p;
    };
    unsigned int*   cnt  = (unsigned int*)alloc((size_t)N * 4);
    float*          dinv = (float*)alloc((size_t)N * 4);
    int*            csr  = (int*)alloc((size_t)N * CAP * 4);
    unsigned short* h    = (unsigned short*)alloc((size_t)N * 128 * 2);
    float*          a    = (float*)alloc((size_t)N * 128 * 4);

    const int nb_n = (N + 255) / 256;
    const int nbF  = (E + 8 * 256 - 1) / (8 * 256);
    const int nbG  = (N + 63) / 64;
    const int nb_g = (N + 15) / 16;

    // cnt=0, then fill (CSR build) co-scheduled with GEMM1 (h = bf16(x@W1))
    k_cnt_init<<<nb_n, 256, 0, stream>>>(cnt, N);
    k_fill_gemm<<<nbF + nbG, 256, 0, stream>>>(src, dst, cnt, csr, E, nbF,
                                               x, W1, h, N, 400);
    k_dinv<<<nb_n, 256, 0, stream>>>(cnt, dinv, N);

    // layer-1 aggregation
    k_gather<<<nb_g, 256, 0, stream>>>(cnt, csr, dinv, h, b1, a, N);

    // layer-2 GEMM (same kernel, no fill part) + aggregation
    k_fill_gemm<<<nbG, 256, 0, stream>>>(src, dst, cnt, csr, 0, 0,
                                         a, W2, h, N, 128);
    k_gather<<<nb_g, 256, 0, stream>>>(cnt, csr, dinv, h, b2, out, N);
}

// Round 6
// 589.520 us; speedup vs baseline: 1.2255x; 1.2255x over previous
//
#include <hip/hip_runtime.h>

// ---------------------------------------------------------------------------
// 2-layer GCN. Round 6: CSR built by bucketed counting sort (no 3.2M global
// atomic RMWs): LDS histograms + ranged reservations + dense per-bucket CSR.
//   h = bf16(x@W)  (unnormalized);  out[d] = relu(dinv[d]*(dinv[d]*h[d] +
//   sum_s dinv[s]*h[s]) + b);  dinv = rsqrt(1+indeg)
// ---------------------------------------------------------------------------

#define NBMAX 1024          // max buckets (128 nodes each) -> N <= 131072
#define HB    128           // blocks for hist/scatter passes

__device__ __forceinline__ unsigned short f2bf(float f) {
    unsigned int u = __float_as_uint(f);
    u += 0x7fffu + ((u >> 16) & 1u);          // round-to-nearest-even
    return (unsigned short)(u >> 16);
}
__device__ __forceinline__ float bflo(unsigned int u) { return __uint_as_float(u << 16); }
__device__ __forceinline__ float bfhi(unsigned int u) { return __uint_as_float(u & 0xffff0000u); }

__global__ __launch_bounds__(256) void k_zero(unsigned int* p, int n) {
    int i = blockIdx.x * 256 + threadIdx.x;
    if (i < n) p[i] = 0u;
}

// Pass 1: bucket histogram (bucket = dst >> 7), LDS-privatized.
__global__ __launch_bounds__(256) void k_bucket_hist(const int* __restrict__ dst,
                                                     unsigned int* __restrict__ bcnt,
                                                     int E, int NB) {
    __shared__ unsigned int hist[NBMAX];
    const int tid = threadIdx.x;
    for (int i = tid; i < NB; i += 256) hist[i] = 0u;
    __syncthreads();
    const int chunk = (E + gridDim.x - 1) / gridDim.x;
    const int e0 = blockIdx.x * chunk;
    const int e1 = min(E, e0 + chunk);
    for (int i = e0 + tid; i < e1; i += 256)
        atomicAdd(&hist[dst[i] >> 7], 1u);
    __syncthreads();
    for (int i = tid; i < NB; i += 256) {
        const unsigned int c = hist[i];
        if (c) atomicAdd(&bcnt[i], c);
    }
}

// Pass 2: single-block exclusive scan of bucket counts -> boff, bcur.
__global__ __launch_bounds__(256) void k_bucket_scan(const unsigned int* __restrict__ bcnt,
                                                     unsigned int* __restrict__ boff,
                                                     unsigned int* __restrict__ bcur,
                                                     int NB, int E) {
    __shared__ unsigned int lds[256];
    const int t = threadIdx.x;
    const int base = t * 4;
    unsigned int v0 = 0, v1 = 0, v2 = 0, v3 = 0;
    if (base + 0 < NB) v0 = bcnt[base + 0];
    if (base + 1 < NB) v1 = bcnt[base + 1];
    if (base + 2 < NB) v2 = bcnt[base + 2];
    if (base + 3 < NB) v3 = bcnt[base + 3];
    const unsigned int s = v0 + v1 + v2 + v3;
    lds[t] = s;
    __syncthreads();
    for (int off = 1; off < 256; off <<= 1) {
        unsigned int v = lds[t];
        unsigned int add = (t >= off) ? lds[t - off] : 0u;
        __syncthreads();
        lds[t] = v + add;
        __syncthreads();
    }
    const unsigned int excl = lds[t] - s;
    const unsigned int e0 = excl, e1 = e0 + v0, e2 = e1 + v1, e3 = e2 + v2;
    if (base + 0 < NB) { boff[base + 0] = e0; bcur[base + 0] = e0; }
    if (base + 1 < NB) { boff[base + 1] = e1; bcur[base + 1] = e1; }
    if (base + 2 < NB) { boff[base + 2] = e2; bcur[base + 2] = e2; }
    if (base + 3 < NB) { boff[base + 3] = e3; bcur[base + 3] = e3; }
    if (t == 255) boff[NB] = (unsigned int)E;
}

// Pass 3: scatter edges grouped by bucket into ebuf (int2 {src,dst}).
// Per-block LDS hist -> one ranged global reservation per (block,bucket).
__global__ __launch_bounds__(256) void k_bucket_scatter(const int* __restrict__ src,
                                                        const int* __restrict__ dst,
                                                        unsigned int* __restrict__ bcur,
                                                        int2* __restrict__ ebuf,
                                                        int E, int NB) {
    __shared__ unsigned int hist[NBMAX];
    __shared__ unsigned int base[NBMAX];
    const int tid = threadIdx.x;
    for (int i = tid; i < NB; i += 256) hist[i] = 0u;
    __syncthreads();
    const int chunk = (E + gridDim.x - 1) / gridDim.x;
    const int e0 = blockIdx.x * chunk;
    const int e1 = min(E, e0 + chunk);
    for (int i = e0 + tid; i < e1; i += 256)
        atomicAdd(&hist[dst[i] >> 7], 1u);
    __syncthreads();
    for (int i = tid; i < NB; i += 256) {
        const unsigned int c = hist[i];
        base[i] = c ? atomicAdd(&bcur[i], c) : 0u;
    }
    __syncthreads();
    for (int i = tid; i < NB; i += 256) hist[i] = 0u;   // reuse as local cursor
    __syncthreads();
    for (int i = e0 + tid; i < e1; i += 256) {
        const int s = src[i];
        const int d = dst[i];
        const int b = d >> 7;
        const unsigned int loc = atomicAdd(&hist[b], 1u);
        ebuf[base[b] + loc] = make_int2(s, d);
    }
}

// Pass 4: one block per bucket -> dense rowptr + dinv + CSR source list.
__global__ __launch_bounds__(256) void k_csr_build(const int2* __restrict__ ebuf,
                                                   const unsigned int* __restrict__ boff,
                                                   int* __restrict__ rowptr,
                                                   float* __restrict__ dinv,
                                                   int* __restrict__ csr_s,
                                                   int N, int NB, int E) {
    __shared__ unsigned int cnt128[128];
    __shared__ unsigned int scan128[128];
    __shared__ unsigned int cur128[128];
    const int tid = threadIdx.x;
    const int b = blockIdx.x;
    const int r0 = (int)boff[b];
    const int r1 = (int)boff[b + 1];

    if (tid < 128) cnt128[tid] = 0u;
    __syncthreads();
    for (int i = r0 + tid; i < r1; i += 256)
        atomicAdd(&cnt128[ebuf[i].y & 127], 1u);
    __syncthreads();

    // exclusive scan of cnt128 (Hillis-Steele inclusive, then subtract)
    if (tid < 128) scan128[tid] = cnt128[tid];
    __syncthreads();
    for (int off = 1; off < 128; off <<= 1) {
        unsigned int v = 0;
        if (tid < 128) {
            v = scan128[tid];
            if (tid >= off) v += scan128[tid - off];
        }
        __syncthreads();
        if (tid < 128) scan128[tid] = v;
        __syncthreads();
    }

    if (tid < 128) {
        const unsigned int deg  = cnt128[tid];
        const unsigned int excl = scan128[tid] - deg;
        cur128[tid] = excl;
        const int node = b * 128 + tid;
        if (node < N) {
            rowptr[node] = r0 + (int)excl;
            dinv[node]   = rsqrtf((float)(deg + 1u));
        }
    }
    if (b == 0 && tid == 0) rowptr[N] = E;
    __syncthreads();

    for (int i = r0 + tid; i < r1; i += 256) {
        const int2 e = ebuf[i];
        const unsigned int p = atomicAdd(&cur128[e.y & 127], 1u);
        csr_s[r0 + (int)p] = e.x;
    }
}

// H[M,128] = bf16( A[M,K] @ B[K,128] ), 128x128 tile, 8x8/thread (2x2 quads).
__global__ __launch_bounds__(256) void k_gemm_h(const float* __restrict__ A,
                                                const float* __restrict__ B,
                                                unsigned short* __restrict__ H,
                                                int M, int K) {
    __shared__ float As[16][128];   // As[k][m]
    __shared__ float Bs[16][128];   // Bs[k][n]
    const int tid = threadIdx.x;
    const int row0 = blockIdx.x * 128;
    const int ty = tid >> 4;
    const int tx = tid & 15;
    const int a_row = tid >> 1;
    const int a_k8  = (tid & 1) * 8;
    const int b_k   = tid >> 4;
    const int b_c8  = (tid & 15) * 8;

    float acc[2][2][4][4] = {};

    for (int kt = 0; kt < K; kt += 16) {
        float4 av0 = make_float4(0.f, 0.f, 0.f, 0.f), av1 = av0;
        const int ar = row0 + a_row;
        if (ar < M) {
            const float* ap = A + (size_t)ar * K + kt + a_k8;
            av0 = *reinterpret_cast<const float4*>(ap);
            av1 = *reinterpret_cast<const float4*>(ap + 4);
        }
        As[a_k8 + 0][a_row] = av0.x; As[a_k8 + 1][a_row] = av0.y;
        As[a_k8 + 2][a_row] = av0.z; As[a_k8 + 3][a_row] = av0.w;
        As[a_k8 + 4][a_row] = av1.x; As[a_k8 + 5][a_row] = av1.y;
        As[a_k8 + 6][a_row] = av1.z; As[a_k8 + 7][a_row] = av1.w;

        const float* bp = B + (size_t)(kt + b_k) * 128 + b_c8;
        *reinterpret_cast<float4*>(&Bs[b_k][b_c8])     = *reinterpret_cast<const float4*>(bp);
        *reinterpret_cast<float4*>(&Bs[b_k][b_c8 + 4]) = *reinterpret_cast<const float4*>(bp + 4);

        __syncthreads();
#pragma unroll
        for (int k = 0; k < 16; ++k) {
            const float4 a0 = *reinterpret_cast<const float4*>(&As[k][ty * 4]);
            const float4 a1 = *reinterpret_cast<const float4*>(&As[k][64 + ty * 4]);
            const float4 b0 = *reinterpret_cast<const float4*>(&Bs[k][tx * 4]);
            const float4 b1 = *reinterpret_cast<const float4*>(&Bs[k][64 + tx * 4]);
            const float ar4[2][4] = {{a0.x, a0.y, a0.z, a0.w}, {a1.x, a1.y, a1.z, a1.w}};
            const float br4[2][4] = {{b0.x, b0.y, b0.z, b0.w}, {b1.x, b1.y, b1.z, b1.w}};
#pragma unroll
            for (int p = 0; p < 2; ++p)
#pragma unroll
                for (int q = 0; q < 2; ++q)
#pragma unroll
                    for (int i = 0; i < 4; ++i)
#pragma unroll
                        for (int j = 0; j < 4; ++j)
                            acc[p][q][i][j] = fmaf(ar4[p][i], br4[q][j], acc[p][q][i][j]);
        }
        __syncthreads();
    }

#pragma unroll
    for (int p = 0; p < 2; ++p)
#pragma unroll
        for (int i = 0; i < 4; ++i) {
            const int r = row0 + p * 64 + ty * 4 + i;
            if (r >= M) continue;
#pragma unroll
            for (int q = 0; q < 2; ++q) {
                const int c = q * 64 + tx * 4;
                ushort4 o;
                o.x = f2bf(acc[p][q][i][0]);
                o.y = f2bf(acc[p][q][i][1]);
                o.z = f2bf(acc[p][q][i][2]);
                o.w = f2bf(acc[p][q][i][3]);
                *reinterpret_cast<ushort4*>(H + (size_t)r * 128 + c) = o;
            }
        }
}

// Pull aggregation over bf16 h rows; per-source dinv in the fma.
// 16 nodes per 256-thread block; 16 lanes per node; 8 cols (16B) per lane.
__global__ __launch_bounds__(256) void k_gather(const int* __restrict__ rowptr,
                                                const int* __restrict__ csr_s,
                                                const float* __restrict__ dinv,
                                                const unsigned short* __restrict__ H,
                                                const float* __restrict__ bias,
                                                float* __restrict__ outp, int N) {
    const int t = threadIdx.x;
    const int node = blockIdx.x * 16 + (t >> 4);
    if (node >= N) return;
    const int lane = t & 15;
    const int c8 = lane * 8;

    const float dv = dinv[node];
    const uint4 hv = *reinterpret_cast<const uint4*>(H + (size_t)node * 128 + c8);
    float acc0 = dv * bflo(hv.x), acc1 = dv * bfhi(hv.x);
    float acc2 = dv * bflo(hv.y), acc3 = dv * bfhi(hv.y);
    float acc4 = dv * bflo(hv.z), acc5 = dv * bfhi(hv.z);
    float acc6 = dv * bflo(hv.w), acc7 = dv * bfhi(hv.w);

    const int beg = rowptr[node], end = rowptr[node + 1];
    for (int r = beg; r < end; r += 16) {
        const int cntc = min(16, end - r);
        int sv = (lane < cntc) ? csr_s[r + lane] : 0;
        for (int j = 0; j < cntc; ++j) {
            const int s = __shfl(sv, j, 16);
            const float w = dinv[s];
            const uint4 x = *reinterpret_cast<const uint4*>(H + (size_t)s * 128 + c8);
            acc0 = fmaf(w, bflo(x.x), acc0); acc1 = fmaf(w, bfhi(x.x), acc1);
            acc2 = fmaf(w, bflo(x.y), acc2); acc3 = fmaf(w, bfhi(x.y), acc3);
            acc4 = fmaf(w, bflo(x.z), acc4); acc5 = fmaf(w, bfhi(x.z), acc5);
            acc6 = fmaf(w, bflo(x.w), acc6); acc7 = fmaf(w, bfhi(x.w), acc7);
        }
    }

    const float4 b0 = *reinterpret_cast<const float4*>(bias + c8);
    const float4 b1 = *reinterpret_cast<const float4*>(bias + c8 + 4);
    float4 o0, o1;
    o0.x = fmaxf(fmaf(acc0, dv, b0.x), 0.f);
    o0.y = fmaxf(fmaf(acc1, dv, b0.y), 0.f);
    o0.z = fmaxf(fmaf(acc2, dv, b0.z), 0.f);
    o0.w = fmaxf(fmaf(acc3, dv, b0.w), 0.f);
    o1.x = fmaxf(fmaf(acc4, dv, b1.x), 0.f);
    o1.y = fmaxf(fmaf(acc5, dv, b1.y), 0.f);
    o1.z = fmaxf(fmaf(acc6, dv, b1.z), 0.f);
    o1.w = fmaxf(fmaf(acc7, dv, b1.w), 0.f);
    float* op = outp + (size_t)node * 128 + c8;
    *reinterpret_cast<float4*>(op)     = o0;
    *reinterpret_cast<float4*>(op + 4) = o1;
}

extern "C" void kernel_launch(void* const* d_in, const int* in_sizes, int n_in,
                              void* d_out, int out_size, void* d_ws, size_t ws_size,
                              hipStream_t stream) {
    const float* x  = (const float*)d_in[0];
    const int*   ei = (const int*)d_in[1];
    const float* W1 = (const float*)d_in[3];
    const float* b1 = (const float*)d_in[4];
    const float* W2 = (const float*)d_in[5];
    const float* b2 = (const float*)d_in[6];
    float* out = (float*)d_out;

    const int N = in_sizes[0] / 400;
    const int E = in_sizes[1] / 2;
    const int* src = ei;
    const int* dst = ei + E;
    const int NB = (N + 127) >> 7;          // 128-node buckets

    char* ws = (char*)d_ws;
    size_t off = 0;
    auto alloc = [&](size_t bytes) {
        void* p = ws + off;
        off = (off + bytes + 255) & ~(size_t)255;
        return p;
    };
    unsigned int*   bcnt   = (unsigned int*)alloc((size_t)NB * 4);
    unsigned int*   boff   = (unsigned int*)alloc((size_t)(NB + 1) * 4);
    unsigned int*   bcur   = (unsigned int*)alloc((size_t)NB * 4);
    int*            rowptr = (int*)alloc((size_t)(N + 1) * 4);
    float*          dinv   = (float*)alloc((size_t)N * 4);
    int*            csr_s  = (int*)alloc((size_t)E * 4);
    unsigned short* h      = (unsigned short*)alloc((size_t)N * 128 * 2);
    float*          a      = (float*)alloc((size_t)N * 128 * 4);
    int2*           ebuf   = (int2*)a;      // alias: dead before gather1 writes a

    const int nb_gm = (N + 127) / 128;
    const int nb_g  = (N + 15) / 16;

    // ---- CSR build via bucketed counting sort ----
    k_zero<<<(NB + 255) / 256, 256, 0, stream>>>(bcnt, NB);
    k_bucket_hist<<<HB, 256, 0, stream>>>(dst, bcnt, E, NB);
    k_bucket_scan<<<1, 256, 0, stream>>>(bcnt, boff, bcur, NB, E);
    k_bucket_scatter<<<HB, 256, 0, stream>>>(src, dst, bcur, ebuf, E, NB);
    k_csr_build<<<NB, 256, 0, stream>>>(ebuf, boff, rowptr, dinv, csr_s, N, NB, E);

    // ---- layer 1 ----
    k_gemm_h<<<nb_gm, 256, 0, stream>>>(x, W1, h, N, 400);
    k_gather<<<nb_g, 256, 0, stream>>>(rowptr, csr_s, dinv, h, b1, a, N);

    // ---- layer 2 ----
    k_gemm_h<<<nb_gm, 256, 0, stream>>>(a, W2, h, N, 128);
    k_gather<<<nb_g, 256, 0, stream>>>(rowptr, csr_s, dinv, h, b2, out, N);
}

// Round 7
// 532.341 us; speedup vs baseline: 1.3572x; 1.1074x over previous
//
#include <hip/hip_runtime.h>

// ---------------------------------------------------------------------------
// 2-layer GCN. Round 7: GEMMs moved to bf16 MFMA (16x16x32), W split hi+lo
// (2 MFMA/product => ~fp32-quality W, bf16-rounded activations).
// CSR built by bucketed counting sort (round 6). h = bf16(x@W) unnormalized;
// out[d] = relu(dinv[d]*(dinv[d]*h[d] + sum_s dinv[s]*h[s]) + b)
// ---------------------------------------------------------------------------

#define NBMAX 1024          // max buckets (128 nodes each) -> N <= 131072
#define HB    128           // blocks for hist/scatter passes

using u16 = unsigned short;
using u32 = unsigned int;
typedef __attribute__((ext_vector_type(8))) short short8;   // 8 bf16
typedef __attribute__((ext_vector_type(4))) float f32x4;

__device__ __forceinline__ u16 f2bf(float f) {
    u32 u = __float_as_uint(f);
    u += 0x7fffu + ((u >> 16) & 1u);          // round-to-nearest-even
    return (u16)(u >> 16);
}
__device__ __forceinline__ u32 pack2(float a, float b) {
    return (u32)f2bf(a) | ((u32)f2bf(b) << 16);
}
__device__ __forceinline__ float bflo(u32 u) { return __uint_as_float(u << 16); }
__device__ __forceinline__ float bfhi(u32 u) { return __uint_as_float(u & 0xffff0000u); }

// ========================= CSR build (round 6) =============================

__global__ __launch_bounds__(256) void k_zero(u32* p, int n) {
    int i = blockIdx.x * 256 + threadIdx.x;
    if (i < n) p[i] = 0u;
}

__global__ __launch_bounds__(256) void k_bucket_hist(const int* __restrict__ dst,
                                                     u32* __restrict__ bcnt,
                                                     int E, int NB) {
    __shared__ u32 hist[NBMAX];
    const int tid = threadIdx.x;
    for (int i = tid; i < NB; i += 256) hist[i] = 0u;
    __syncthreads();
    const int chunk = (E + gridDim.x - 1) / gridDim.x;
    const int e0 = blockIdx.x * chunk;
    const int e1 = min(E, e0 + chunk);
    for (int i = e0 + tid; i < e1; i += 256)
        atomicAdd(&hist[dst[i] >> 7], 1u);
    __syncthreads();
    for (int i = tid; i < NB; i += 256) {
        const u32 c = hist[i];
        if (c) atomicAdd(&bcnt[i], c);
    }
}

__global__ __launch_bounds__(256) void k_bucket_scan(const u32* __restrict__ bcnt,
                                                     u32* __restrict__ boff,
                                                     u32* __restrict__ bcur,
                                                     int NB, int E) {
    __shared__ u32 lds[256];
    const int t = threadIdx.x;
    const int base = t * 4;
    u32 v0 = 0, v1 = 0, v2 = 0, v3 = 0;
    if (base + 0 < NB) v0 = bcnt[base + 0];
    if (base + 1 < NB) v1 = bcnt[base + 1];
    if (base + 2 < NB) v2 = bcnt[base + 2];
    if (base + 3 < NB) v3 = bcnt[base + 3];
    const u32 s = v0 + v1 + v2 + v3;
    lds[t] = s;
    __syncthreads();
    for (int off = 1; off < 256; off <<= 1) {
        u32 v = lds[t];
        u32 add = (t >= off) ? lds[t - off] : 0u;
        __syncthreads();
        lds[t] = v + add;
        __syncthreads();
    }
    const u32 excl = lds[t] - s;
    const u32 e0 = excl, e1 = e0 + v0, e2 = e1 + v1, e3 = e2 + v2;
    if (base + 0 < NB) { boff[base + 0] = e0; bcur[base + 0] = e0; }
    if (base + 1 < NB) { boff[base + 1] = e1; bcur[base + 1] = e1; }
    if (base + 2 < NB) { boff[base + 2] = e2; bcur[base + 2] = e2; }
    if (base + 3 < NB) { boff[base + 3] = e3; bcur[base + 3] = e3; }
    if (t == 255) boff[NB] = (u32)E;
}

__global__ __launch_bounds__(256) void k_bucket_scatter(const int* __restrict__ src,
                                                        const int* __restrict__ dst,
                                                        u32* __restrict__ bcur,
                                                        int2* __restrict__ ebuf,
                                                        int E, int NB) {
    __shared__ u32 hist[NBMAX];
    __shared__ u32 base[NBMAX];
    const int tid = threadIdx.x;
    for (int i = tid; i < NB; i += 256) hist[i] = 0u;
    __syncthreads();
    const int chunk = (E + gridDim.x - 1) / gridDim.x;
    const int e0 = blockIdx.x * chunk;
    const int e1 = min(E, e0 + chunk);
    for (int i = e0 + tid; i < e1; i += 256)
        atomicAdd(&hist[dst[i] >> 7], 1u);
    __syncthreads();
    for (int i = tid; i < NB; i += 256) {
        const u32 c = hist[i];
        base[i] = c ? atomicAdd(&bcur[i], c) : 0u;
    }
    __syncthreads();
    for (int i = tid; i < NB; i += 256) hist[i] = 0u;   // reuse as local cursor
    __syncthreads();
    for (int i = e0 + tid; i < e1; i += 256) {
        const int s = src[i];
        const int d = dst[i];
        const int b = d >> 7;
        const u32 loc = atomicAdd(&hist[b], 1u);
        ebuf[base[b] + loc] = make_int2(s, d);
    }
}

__global__ __launch_bounds__(256) void k_csr_build(const int2* __restrict__ ebuf,
                                                   const u32* __restrict__ boff,
                                                   int* __restrict__ rowptr,
                                                   float* __restrict__ dinv,
                                                   int* __restrict__ csr_s,
                                                   int N, int NB, int E) {
    __shared__ u32 cnt128[128];
    __shared__ u32 scan128[128];
    __shared__ u32 cur128[128];
    const int tid = threadIdx.x;
    const int b = blockIdx.x;
    const int r0 = (int)boff[b];
    const int r1 = (int)boff[b + 1];

    if (tid < 128) cnt128[tid] = 0u;
    __syncthreads();
    for (int i = r0 + tid; i < r1; i += 256)
        atomicAdd(&cnt128[ebuf[i].y & 127], 1u);
    __syncthreads();

    if (tid < 128) scan128[tid] = cnt128[tid];
    __syncthreads();
    for (int off = 1; off < 128; off <<= 1) {
        u32 v = 0;
        if (tid < 128) {
            v = scan128[tid];
            if (tid >= off) v += scan128[tid - off];
        }
        __syncthreads();
        if (tid < 128) scan128[tid] = v;
        __syncthreads();
    }

    if (tid < 128) {
        const u32 deg  = cnt128[tid];
        const u32 excl = scan128[tid] - deg;
        cur128[tid] = excl;
        const int node = b * 128 + tid;
        if (node < N) {
            rowptr[node] = r0 + (int)excl;
            dinv[node]   = rsqrtf((float)(deg + 1u));
        }
    }
    if (b == 0 && tid == 0) rowptr[N] = E;
    __syncthreads();

    for (int i = r0 + tid; i < r1; i += 256) {
        const int2 e = ebuf[i];
        const u32 p = atomicAdd(&cur128[e.y & 127], 1u);
        csr_s[r0 + (int)p] = e.x;
    }
}

// ===================== W prep: transpose + hi/lo split =====================
// Wt_hi/Wt_lo [128][KP] bf16, zero-padded k >= K.
__global__ __launch_bounds__(256) void k_wprep(const float* __restrict__ W,
                                               u16* __restrict__ Whi,
                                               u16* __restrict__ Wlo,
                                               int K, int KP) {
    int idx = blockIdx.x * 256 + threadIdx.x;
    if (idx >= 128 * KP) return;
    int n = idx / KP, k = idx - n * KP;
    float w = (k < K) ? W[(size_t)k * 128 + n] : 0.f;
    u16 hi = f2bf(w);
    float hif = __uint_as_float((u32)hi << 16);
    u16 lo = f2bf(w - hif);
    Whi[idx] = hi;
    Wlo[idx] = lo;
}

// ===================== MFMA GEMM: H[M,128] = bf16(A @ W) ===================
// 128x128 tile, 4 waves (2x2), mfma_f32_16x16x32_bf16, W split hi+lo.
// ABF=0: A fp32 (converted to bf16 in staging); ABF=1: A already bf16.
template <int ABF>
__global__ __launch_bounds__(256) void k_gemm_mfma(
        const void* __restrict__ Aptr,
        const u16* __restrict__ Whi, const u16* __restrict__ Wlo,
        u16* __restrict__ H, int M, int K, int KP) {
    __shared__ u16 smem[3 * 128 * 40];
    u16* As = smem;                    // [128][40]  (pad: stride 40 bf16)
    u16* Bh = smem + 128 * 40;         // [128 cols][40]
    u16* Bl = smem + 2 * 128 * 40;
    const int LSTR = 40;

    const int tid = threadIdx.x;
    const int row0 = blockIdx.x * 128;
    const int wid = tid >> 6;
    const int lane = tid & 63;
    const int wm = wid >> 1, wn = wid & 1;
    const int l15 = lane & 15, lg = lane >> 4;

    const int arow = tid >> 1;
    const int ak0  = (tid & 1) * 16;
    const int grow = row0 + arow;
    const int bmat = tid >> 7;          // 0=hi, 1=lo
    const int bcol = tid & 127;
    const u16* Wsrc = bmat ? Wlo : Whi;
    u16* Bdst = bmat ? Bl : Bh;
    const int NT = KP >> 5;

    float4 ar0, ar1, ar2, ar3;          // fp32-A staging regs
    uint4  au0, au1;                    // bf16-A staging regs
    uint4  bu0, bu1, bu2, bu3;          // W staging regs

    auto load_tile = [&](int kt) {
        const int k0 = kt * 32 + ak0;
        if (ABF) {
            if (grow < M) {
                const u16* ap = (const u16*)Aptr + (size_t)grow * K + k0;
                au0 = *reinterpret_cast<const uint4*>(ap);
                au1 = *reinterpret_cast<const uint4*>(ap + 8);
            } else {
                au0 = make_uint4(0, 0, 0, 0);
                au1 = make_uint4(0, 0, 0, 0);
            }
        } else {
            if (grow < M && k0 < K) {
                const float* ap = (const float*)Aptr + (size_t)grow * K + k0;
                ar0 = *reinterpret_cast<const float4*>(ap);
                ar1 = *reinterpret_cast<const float4*>(ap + 4);
                ar2 = *reinterpret_cast<const float4*>(ap + 8);
                ar3 = *reinterpret_cast<const float4*>(ap + 12);
            } else {
                ar0 = ar1 = ar2 = ar3 = make_float4(0.f, 0.f, 0.f, 0.f);
            }
        }
        const u16* wp = Wsrc + (size_t)bcol * KP + kt * 32;
        bu0 = *reinterpret_cast<const uint4*>(wp);
        bu1 = *reinterpret_cast<const uint4*>(wp + 8);
        bu2 = *reinterpret_cast<const uint4*>(wp + 16);
        bu3 = *reinterpret_cast<const uint4*>(wp + 24);
    };

    auto store_tile = [&]() {
        u16* ad = As + arow * LSTR + ak0;
        if (ABF) {
            *reinterpret_cast<uint4*>(ad)     = au0;
            *reinterpret_cast<uint4*>(ad + 8) = au1;
        } else {
            uint4 w0, w1;
            w0.x = pack2(ar0.x, ar0.y); w0.y = pack2(ar0.z, ar0.w);
            w0.z = pack2(ar1.x, ar1.y); w0.w = pack2(ar1.z, ar1.w);
            w1.x = pack2(ar2.x, ar2.y); w1.y = pack2(ar2.z, ar2.w);
            w1.z = pack2(ar3.x, ar3.y); w1.w = pack2(ar3.z, ar3.w);
            *reinterpret_cast<uint4*>(ad)     = w0;
            *reinterpret_cast<uint4*>(ad + 8) = w1;
        }
        u16* bd = Bdst + bcol * LSTR;
        *reinterpret_cast<uint4*>(bd)      = bu0;
        *reinterpret_cast<uint4*>(bd + 8)  = bu1;
        *reinterpret_cast<uint4*>(bd + 16) = bu2;
        *reinterpret_cast<uint4*>(bd + 24) = bu3;
    };

    f32x4 acc[4][4];
#pragma unroll
    for (int i = 0; i < 4; ++i)
#pragma unroll
        for (int j = 0; j < 4; ++j)
            acc[i][j] = (f32x4){0.f, 0.f, 0.f, 0.f};

    load_tile(0);
    for (int kt = 0; kt < NT; ++kt) {
        __syncthreads();
        store_tile();
        __syncthreads();
        if (kt + 1 < NT) load_tile(kt + 1);   // prefetch under MFMA
        short8 af[4], bhf[4], blf[4];
#pragma unroll
        for (int i = 0; i < 4; ++i)
            af[i] = *reinterpret_cast<const short8*>(
                As + (wm * 64 + i * 16 + l15) * LSTR + lg * 8);
#pragma unroll
        for (int j = 0; j < 4; ++j) {
            bhf[j] = *reinterpret_cast<const short8*>(
                Bh + (wn * 64 + j * 16 + l15) * LSTR + lg * 8);
            blf[j] = *reinterpret_cast<const short8*>(
                Bl + (wn * 64 + j * 16 + l15) * LSTR + lg * 8);
        }
#pragma unroll
        for (int i = 0; i < 4; ++i)
#pragma unroll
            for (int j = 0; j < 4; ++j) {
                acc[i][j] = __builtin_amdgcn_mfma_f32_16x16x32_bf16(
                    af[i], bhf[j], acc[i][j], 0, 0, 0);
                acc[i][j] = __builtin_amdgcn_mfma_f32_16x16x32_bf16(
                    af[i], blf[j], acc[i][j], 0, 0, 0);
            }
    }

    // Epilogue: stage bf16 C-tile through LDS for coalesced 16B global stores.
    const int CSTR = 136;
    __syncthreads();
#pragma unroll
    for (int half = 0; half < 2; ++half) {
        if (wm == half) {
#pragma unroll
            for (int i = 0; i < 4; ++i)
#pragma unroll
                for (int j = 0; j < 4; ++j)
#pragma unroll
                    for (int r = 0; r < 4; ++r)
                        smem[(i * 16 + lg * 4 + r) * CSTR + wn * 64 + j * 16 + l15] =
                            f2bf(acc[i][j][r]);
        }
        __syncthreads();
        {
            const int rr = tid >> 2;
            const int cc = (tid & 3) * 32;
            const int gr = row0 + half * 64 + rr;
            if (gr < M) {
                const u16* cp = smem + rr * CSTR + cc;
                uint4 q0 = *reinterpret_cast<const uint4*>(cp);
                uint4 q1 = *reinterpret_cast<const uint4*>(cp + 8);
                uint4 q2 = *reinterpret_cast<const uint4*>(cp + 16);
                uint4 q3 = *reinterpret_cast<const uint4*>(cp + 24);
                uint4* hp = reinterpret_cast<uint4*>(H + (size_t)gr * 128 + cc);
                hp[0] = q0; hp[1] = q1; hp[2] = q2; hp[3] = q3;
            }
        }
        __syncthreads();
    }
}

// ========================= gather (pull aggregation) =======================
// OUTBF=1: write bf16; OUTBF=0: write fp32.
template <int OUTBF>
__global__ __launch_bounds__(256) void k_gather(const int* __restrict__ rowptr,
                                                const int* __restrict__ csr_s,
                                                const float* __restrict__ dinv,
                                                const u16* __restrict__ H,
                                                const float* __restrict__ bias,
                                                void* __restrict__ outp, int N) {
    const int t = threadIdx.x;
    const int node = blockIdx.x * 16 + (t >> 4);
    if (node >= N) return;
    const int lane = t & 15;
    const int c8 = lane * 8;

    const float dv = dinv[node];
    const uint4 hv = *reinterpret_cast<const uint4*>(H + (size_t)node * 128 + c8);
    float acc0 = dv * bflo(hv.x), acc1 = dv * bfhi(hv.x);
    float acc2 = dv * bflo(hv.y), acc3 = dv * bfhi(hv.y);
    float acc4 = dv * bflo(hv.z), acc5 = dv * bfhi(hv.z);
    float acc6 = dv * bflo(hv.w), acc7 = dv * bfhi(hv.w);

    const int beg = rowptr[node], end = rowptr[node + 1];
    for (int r = beg; r < end; r += 16) {
        const int cntc = min(16, end - r);
        int sv = (lane < cntc) ? csr_s[r + lane] : 0;
        for (int j = 0; j < cntc; ++j) {
            const int s = __shfl(sv, j, 16);
            const float w = dinv[s];
            const uint4 x = *reinterpret_cast<const uint4*>(H + (size_t)s * 128 + c8);
            acc0 = fmaf(w, bflo(x.x), acc0); acc1 = fmaf(w, bfhi(x.x), acc1);
            acc2 = fmaf(w, bflo(x.y), acc2); acc3 = fmaf(w, bfhi(x.y), acc3);
            acc4 = fmaf(w, bflo(x.z), acc4); acc5 = fmaf(w, bfhi(x.z), acc5);
            acc6 = fmaf(w, bflo(x.w), acc6); acc7 = fmaf(w, bfhi(x.w), acc7);
        }
    }

    const float4 b0 = *reinterpret_cast<const float4*>(bias + c8);
    const float4 b1 = *reinterpret_cast<const float4*>(bias + c8 + 4);
    const float r0 = fmaxf(fmaf(acc0, dv, b0.x), 0.f);
    const float r1 = fmaxf(fmaf(acc1, dv, b0.y), 0.f);
    const float r2 = fmaxf(fmaf(acc2, dv, b0.z), 0.f);
    const float r3 = fmaxf(fmaf(acc3, dv, b0.w), 0.f);
    const float r4 = fmaxf(fmaf(acc4, dv, b1.x), 0.f);
    const float r5 = fmaxf(fmaf(acc5, dv, b1.y), 0.f);
    const float r6 = fmaxf(fmaf(acc6, dv, b1.z), 0.f);
    const float r7 = fmaxf(fmaf(acc7, dv, b1.w), 0.f);

    if (OUTBF) {
        uint4 q;
        q.x = pack2(r0, r1); q.y = pack2(r2, r3);
        q.z = pack2(r4, r5); q.w = pack2(r6, r7);
        u16* op = (u16*)outp + (size_t)node * 128 + c8;
        *reinterpret_cast<uint4*>(op) = q;
    } else {
        float* op = (float*)outp + (size_t)node * 128 + c8;
        *reinterpret_cast<float4*>(op)     = make_float4(r0, r1, r2, r3);
        *reinterpret_cast<float4*>(op + 4) = make_float4(r4, r5, r6, r7);
    }
}

// ===========================================================================

extern "C" void kernel_launch(void* const* d_in, const int* in_sizes, int n_in,
                              void* d_out, int out_size, void* d_ws, size_t ws_size,
                              hipStream_t stream) {
    const float* x  = (const float*)d_in[0];
    const int*   ei = (const int*)d_in[1];
    const float* W1 = (const float*)d_in[3];
    const float* b1 = (const float*)d_in[4];
    const float* W2 = (const float*)d_in[5];
    const float* b2 = (const float*)d_in[6];
    float* out = (float*)d_out;

    const int N = in_sizes[0] / 400;
    const int E = in_sizes[1] / 2;
    const int* src = ei;
    const int* dst = ei + E;
    const int NB = (N + 127) >> 7;
    const int KP1 = 416;                // 400 padded to 13*32
    const int KP2 = 128;

    char* ws = (char*)d_ws;
    size_t off = 0;
    auto alloc = [&](size_t bytes) {
        void* p = ws + off;
        off = (off + bytes + 255) & ~(size_t)255;
        return p;
    };
    u32*   bcnt   = (u32*)alloc((size_t)NB * 4);
    u32*   boff   = (u32*)alloc((size_t)(NB + 1) * 4);
    u32*   bcur   = (u32*)alloc((size_t)NB * 4);
    int*   rowptr = (int*)alloc((size_t)(N + 1) * 4);
    float* dinv   = (float*)alloc((size_t)N * 4);
    int*   csr_s  = (int*)alloc((size_t)E * 4);
    u16*   h      = (u16*)alloc((size_t)N * 128 * 2);
    u16*   abf    = (u16*)alloc((size_t)N * 128 * 2);
    int2*  ebuf   = (int2*)alloc((size_t)E * 8);
    u16*   Whi1   = (u16*)alloc((size_t)128 * KP1 * 2);
    u16*   Wlo1   = (u16*)alloc((size_t)128 * KP1 * 2);
    u16*   Whi2   = (u16*)alloc((size_t)128 * KP2 * 2);
    u16*   Wlo2   = (u16*)alloc((size_t)128 * KP2 * 2);

    const int nb_gm = (N + 127) / 128;
    const int nb_g  = (N + 15) / 16;

    // ---- W prep (tiny) ----
    k_wprep<<<(128 * KP1 + 255) / 256, 256, 0, stream>>>(W1, Whi1, Wlo1, 400, KP1);
    k_wprep<<<(128 * KP2 + 255) / 256, 256, 0, stream>>>(W2, Whi2, Wlo2, 128, KP2);

    // ---- CSR build via bucketed counting sort ----
    k_zero<<<(NB + 255) / 256, 256, 0, stream>>>(bcnt, NB);
    k_bucket_hist<<<HB, 256, 0, stream>>>(dst, bcnt, E, NB);
    k_bucket_scan<<<1, 256, 0, stream>>>(bcnt, boff, bcur, NB, E);
    k_bucket_scatter<<<HB, 256, 0, stream>>>(src, dst, bcur, ebuf, E, NB);
    k_csr_build<<<NB, 256, 0, stream>>>(ebuf, boff, rowptr, dinv, csr_s, N, NB, E);

    // ---- layer 1 ----
    k_gemm_mfma<0><<<nb_gm, 256, 0, stream>>>(x, Whi1, Wlo1, h, N, 400, KP1);
    k_gather<1><<<nb_g, 256, 0, stream>>>(rowptr, csr_s, dinv, h, b1, abf, N);

    // ---- layer 2 ----
    k_gemm_mfma<1><<<nb_gm, 256, 0, stream>>>(abf, Whi2, Wlo2, h, N, 128, KP2);
    k_gather<0><<<nb_g, 256, 0, stream>>>(rowptr, csr_s, dinv, h, b2, out, N);
}

// Round 8
// 457.344 us; speedup vs baseline: 1.5797x; 1.1640x over previous
//
#include <hip/hip_runtime.h>

// ---------------------------------------------------------------------------
// 2-layer GCN. Round 8: MFMA GEMM restructured — single bf16 W (no hi/lo),
// BK=64, 512-thread blocks (8 waves, 2x4), wave tile 64x32 (32 AGPR),
// dense LDS + XOR swizzle (conflict-free ds_read_b128), 4 blocks/CU.
// CSR via bucketed counting sort (round 6). h = bf16(x@W) unnormalized;
// out[d] = relu(dinv[d]*(dinv[d]*h[d] + sum_s dinv[s]*h[s]) + b)
// ---------------------------------------------------------------------------

#define NBMAX 1024          // max buckets (128 nodes each) -> N <= 131072
#define HB    128           // blocks for hist/scatter passes

using u16 = unsigned short;
using u32 = unsigned int;
typedef __attribute__((ext_vector_type(8))) short short8;   // 8 bf16
typedef __attribute__((ext_vector_type(4))) float f32x4;

__device__ __forceinline__ u16 f2bf(float f) {
    u32 u = __float_as_uint(f);
    u += 0x7fffu + ((u >> 16) & 1u);          // round-to-nearest-even
    return (u16)(u >> 16);
}
__device__ __forceinline__ u32 pack2(float a, float b) {
    return (u32)f2bf(a) | ((u32)f2bf(b) << 16);
}
__device__ __forceinline__ float bflo(u32 u) { return __uint_as_float(u << 16); }
__device__ __forceinline__ float bfhi(u32 u) { return __uint_as_float(u & 0xffff0000u); }

// ========================= CSR build (round 6) =============================

__global__ __launch_bounds__(256) void k_zero(u32* p, int n) {
    int i = blockIdx.x * 256 + threadIdx.x;
    if (i < n) p[i] = 0u;
}

__global__ __launch_bounds__(256) void k_bucket_hist(const int* __restrict__ dst,
                                                     u32* __restrict__ bcnt,
                                                     int E, int NB) {
    __shared__ u32 hist[NBMAX];
    const int tid = threadIdx.x;
    for (int i = tid; i < NB; i += 256) hist[i] = 0u;
    __syncthreads();
    const int chunk = (E + gridDim.x - 1) / gridDim.x;
    const int e0 = blockIdx.x * chunk;
    const int e1 = min(E, e0 + chunk);
    for (int i = e0 + tid; i < e1; i += 256)
        atomicAdd(&hist[dst[i] >> 7], 1u);
    __syncthreads();
    for (int i = tid; i < NB; i += 256) {
        const u32 c = hist[i];
        if (c) atomicAdd(&bcnt[i], c);
    }
}

__global__ __launch_bounds__(256) void k_bucket_scan(const u32* __restrict__ bcnt,
                                                     u32* __restrict__ boff,
                                                     u32* __restrict__ bcur,
                                                     int NB, int E) {
    __shared__ u32 lds[256];
    const int t = threadIdx.x;
    const int base = t * 4;
    u32 v0 = 0, v1 = 0, v2 = 0, v3 = 0;
    if (base + 0 < NB) v0 = bcnt[base + 0];
    if (base + 1 < NB) v1 = bcnt[base + 1];
    if (base + 2 < NB) v2 = bcnt[base + 2];
    if (base + 3 < NB) v3 = bcnt[base + 3];
    const u32 s = v0 + v1 + v2 + v3;
    lds[t] = s;
    __syncthreads();
    for (int off = 1; off < 256; off <<= 1) {
        u32 v = lds[t];
        u32 add = (t >= off) ? lds[t - off] : 0u;
        __syncthreads();
        lds[t] = v + add;
        __syncthreads();
    }
    const u32 excl = lds[t] - s;
    const u32 e0 = excl, e1 = e0 + v0, e2 = e1 + v1, e3 = e2 + v2;
    if (base + 0 < NB) { boff[base + 0] = e0; bcur[base + 0] = e0; }
    if (base + 1 < NB) { boff[base + 1] = e1; bcur[base + 1] = e1; }
    if (base + 2 < NB) { boff[base + 2] = e2; bcur[base + 2] = e2; }
    if (base + 3 < NB) { boff[base + 3] = e3; bcur[base + 3] = e3; }
    if (t == 255) boff[NB] = (u32)E;
}

__global__ __launch_bounds__(256) void k_bucket_scatter(const int* __restrict__ src,
                                                        const int* __restrict__ dst,
                                                        u32* __restrict__ bcur,
                                                        int2* __restrict__ ebuf,
                                                        int E, int NB) {
    __shared__ u32 hist[NBMAX];
    __shared__ u32 base[NBMAX];
    const int tid = threadIdx.x;
    for (int i = tid; i < NB; i += 256) hist[i] = 0u;
    __syncthreads();
    const int chunk = (E + gridDim.x - 1) / gridDim.x;
    const int e0 = blockIdx.x * chunk;
    const int e1 = min(E, e0 + chunk);
    for (int i = e0 + tid; i < e1; i += 256)
        atomicAdd(&hist[dst[i] >> 7], 1u);
    __syncthreads();
    for (int i = tid; i < NB; i += 256) {
        const u32 c = hist[i];
        base[i] = c ? atomicAdd(&bcur[i], c) : 0u;
    }
    __syncthreads();
    for (int i = tid; i < NB; i += 256) hist[i] = 0u;   // reuse as local cursor
    __syncthreads();
    for (int i = e0 + tid; i < e1; i += 256) {
        const int s = src[i];
        const int d = dst[i];
        const int b = d >> 7;
        const u32 loc = atomicAdd(&hist[b], 1u);
        ebuf[base[b] + loc] = make_int2(s, d);
    }
}

__global__ __launch_bounds__(256) void k_csr_build(const int2* __restrict__ ebuf,
                                                   const u32* __restrict__ boff,
                                                   int* __restrict__ rowptr,
                                                   float* __restrict__ dinv,
                                                   int* __restrict__ csr_s,
                                                   int N, int NB, int E) {
    __shared__ u32 cnt128[128];
    __shared__ u32 scan128[128];
    __shared__ u32 cur128[128];
    const int tid = threadIdx.x;
    const int b = blockIdx.x;
    const int r0 = (int)boff[b];
    const int r1 = (int)boff[b + 1];

    if (tid < 128) cnt128[tid] = 0u;
    __syncthreads();
    for (int i = r0 + tid; i < r1; i += 256)
        atomicAdd(&cnt128[ebuf[i].y & 127], 1u);
    __syncthreads();

    if (tid < 128) scan128[tid] = cnt128[tid];
    __syncthreads();
    for (int off = 1; off < 128; off <<= 1) {
        u32 v = 0;
        if (tid < 128) {
            v = scan128[tid];
            if (tid >= off) v += scan128[tid - off];
        }
        __syncthreads();
        if (tid < 128) scan128[tid] = v;
        __syncthreads();
    }

    if (tid < 128) {
        const u32 deg  = cnt128[tid];
        const u32 excl = scan128[tid] - deg;
        cur128[tid] = excl;
        const int node = b * 128 + tid;
        if (node < N) {
            rowptr[node] = r0 + (int)excl;
            dinv[node]   = rsqrtf((float)(deg + 1u));
        }
    }
    if (b == 0 && tid == 0) rowptr[N] = E;
    __syncthreads();

    for (int i = r0 + tid; i < r1; i += 256) {
        const int2 e = ebuf[i];
        const u32 p = atomicAdd(&cur128[e.y & 127], 1u);
        csr_s[r0 + (int)p] = e.x;
    }
}

// ===================== W prep: transpose to [128][KP] bf16 =================
__global__ __launch_bounds__(256) void k_wprep(const float* __restrict__ W,
                                               u16* __restrict__ Wt,
                                               int K, int KP) {
    int idx = blockIdx.x * 256 + threadIdx.x;
    if (idx >= 128 * KP) return;
    int n = idx / KP, k = idx - n * KP;
    Wt[idx] = (k < K) ? f2bf(W[(size_t)k * 128 + n]) : (u16)0;
}

// ===================== MFMA GEMM: H[M,128] = bf16(A @ W) ===================
// 128x128 tile, 512 threads (8 waves 2x4), wave tile 64x32, BK=64.
// LDS: As[128][64], Bs[128][64] bf16, XOR-swizzled on 16B slots (slot ^= row&7).
// ABF=0: A fp32 (converted in staging); ABF=1: A already bf16.
template <int ABF>
__global__ __launch_bounds__(512) void k_gemm_mfma(
        const void* __restrict__ Aptr,
        const u16* __restrict__ Wt,
        u16* __restrict__ H, int M, int K, int KP) {
    __shared__ u16 smem[16384];        // 32 KB: As | Bs, reused by epilogue
    u16* As = smem;                    // [128][64]
    u16* Bs = smem + 128 * 64;         // [128][64]

    const int tid = threadIdx.x;
    const int row0 = blockIdx.x * 128;
    const int wid = tid >> 6;
    const int lane = tid & 63;
    const int wm = wid >> 2, wn = wid & 3;    // 2 x 4 wave grid
    const int l15 = lane & 15, lg = lane >> 4;
    const int lr7 = l15 & 7;

    const int arow = tid >> 2;                // 0..127 (row for A, col for B)
    const int achk = tid & 3;                 // 16-elem k-chunk
    const int grow = row0 + arow;
    const int ar7 = arow & 7;
    const int s0 = (achk * 2) ^ ar7;          // swizzled 16B slot indices
    const int s1 = (achk * 2 + 1) ^ ar7;

    float4 ar0, ar1, ar2, ar3;                // fp32-A staging
    uint4  au0, au1;                          // bf16-A staging
    uint4  bu0, bu1;                          // W staging

    auto load_tile = [&](int kt) {
        const int k0 = kt * 64 + achk * 16;
        if (ABF) {
            if (grow < M) {
                const u16* ap = (const u16*)Aptr + (size_t)grow * K + k0;
                au0 = *reinterpret_cast<const uint4*>(ap);
                au1 = *reinterpret_cast<const uint4*>(ap + 8);
            } else {
                au0 = make_uint4(0, 0, 0, 0);
                au1 = make_uint4(0, 0, 0, 0);
            }
        } else {
            if (grow < M && k0 < K) {       // K multiple of 16: chunks never straddle
                const float* ap = (const float*)Aptr + (size_t)grow * K + k0;
                ar0 = *reinterpret_cast<const float4*>(ap);
                ar1 = *reinterpret_cast<const float4*>(ap + 4);
                ar2 = *reinterpret_cast<const float4*>(ap + 8);
                ar3 = *reinterpret_cast<const float4*>(ap + 12);
            } else {
                ar0 = ar1 = ar2 = ar3 = make_float4(0.f, 0.f, 0.f, 0.f);
            }
        }
        const u16* wp = Wt + (size_t)arow * KP + k0;    // arow doubles as bcol
        bu0 = *reinterpret_cast<const uint4*>(wp);
        bu1 = *reinterpret_cast<const uint4*>(wp + 8);
    };

    auto store_tile = [&]() {
        uint4 w0, w1;
        if (ABF) {
            w0 = au0; w1 = au1;
        } else {
            w0.x = pack2(ar0.x, ar0.y); w0.y = pack2(ar0.z, ar0.w);
            w0.z = pack2(ar1.x, ar1.y); w0.w = pack2(ar1.z, ar1.w);
            w1.x = pack2(ar2.x, ar2.y); w1.y = pack2(ar2.z, ar2.w);
            w1.z = pack2(ar3.x, ar3.y); w1.w = pack2(ar3.z, ar3.w);
        }
        u16* ad = As + arow * 64;
        *reinterpret_cast<uint4*>(ad + s0 * 8) = w0;
        *reinterpret_cast<uint4*>(ad + s1 * 8) = w1;
        u16* bd = Bs + arow * 64;
        *reinterpret_cast<uint4*>(bd + s0 * 8) = bu0;
        *reinterpret_cast<uint4*>(bd + s1 * 8) = bu1;
    };

    f32x4 acc[4][2];
#pragma unroll
    for (int i = 0; i < 4; ++i)
#pragma unroll
        for (int j = 0; j < 2; ++j)
            acc[i][j] = (f32x4){0.f, 0.f, 0.f, 0.f};

    const int NT = KP >> 6;
    load_tile(0);
    for (int kt = 0; kt < NT; ++kt) {
        __syncthreads();
        store_tile();
        __syncthreads();
        if (kt + 1 < NT) load_tile(kt + 1);   // reg prefetch under MFMA
#pragma unroll
        for (int sub = 0; sub < 2; ++sub) {
            const int slot = ((sub * 4 + lg) ^ lr7) * 8;
            short8 af[4], bf[2];
#pragma unroll
            for (int i = 0; i < 4; ++i)
                af[i] = *reinterpret_cast<const short8*>(
                    As + (wm * 64 + i * 16 + l15) * 64 + slot);
#pragma unroll
            for (int j = 0; j < 2; ++j)
                bf[j] = *reinterpret_cast<const short8*>(
                    Bs + (wn * 32 + j * 16 + l15) * 64 + slot);
#pragma unroll
            for (int i = 0; i < 4; ++i)
#pragma unroll
                for (int j = 0; j < 2; ++j)
                    acc[i][j] = __builtin_amdgcn_mfma_f32_16x16x32_bf16(
                        af[i], bf[j], acc[i][j], 0, 0, 0);
        }
    }

    // Epilogue: stage bf16 C through LDS (CSTR=136, 16B-aligned) -> 32B stores.
    const int CSTR = 136;
    __syncthreads();
#pragma unroll
    for (int half = 0; half < 2; ++half) {
        if (wm == half) {
#pragma unroll
            for (int i = 0; i < 4; ++i)
#pragma unroll
                for (int j = 0; j < 2; ++j)
#pragma unroll
                    for (int r = 0; r < 4; ++r)
                        smem[(i * 16 + lg * 4 + r) * CSTR + wn * 32 + j * 16 + l15] =
                            f2bf(acc[i][j][r]);
        }
        __syncthreads();
        {
            const int rr = tid >> 3;            // 0..63
            const int cc = (tid & 7) * 16;      // 0..112
            const int gr = row0 + half * 64 + rr;
            if (gr < M) {
                const u16* cp = smem + rr * CSTR + cc;
                uint4 q0 = *reinterpret_cast<const uint4*>(cp);
                uint4 q1 = *reinterpret_cast<const uint4*>(cp + 8);
                uint4* hp = reinterpret_cast<uint4*>(H + (size_t)gr * 128 + cc);
                hp[0] = q0; hp[1] = q1;
            }
        }
        __syncthreads();
    }
}

// ========================= gather (pull aggregation) =======================
template <int OUTBF>
__global__ __launch_bounds__(256) void k_gather(const int* __restrict__ rowptr,
                                                const int* __restrict__ csr_s,
                                                const float* __restrict__ dinv,
                                                const u16* __restrict__ H,
                                                const float* __restrict__ bias,
                                                void* __restrict__ outp, int N) {
    const int t = threadIdx.x;
    const int node = blockIdx.x * 16 + (t >> 4);
    if (node >= N) return;
    const int lane = t & 15;
    const int c8 = lane * 8;

    const float dv = dinv[node];
    const uint4 hv = *reinterpret_cast<const uint4*>(H + (size_t)node * 128 + c8);
    float acc0 = dv * bflo(hv.x), acc1 = dv * bfhi(hv.x);
    float acc2 = dv * bflo(hv.y), acc3 = dv * bfhi(hv.y);
    float acc4 = dv * bflo(hv.z), acc5 = dv * bfhi(hv.z);
    float acc6 = dv * bflo(hv.w), acc7 = dv * bfhi(hv.w);

    const int beg = rowptr[node], end = rowptr[node + 1];
    for (int r = beg; r < end; r += 16) {
        const int cntc = min(16, end - r);
        int sv = (lane < cntc) ? csr_s[r + lane] : 0;
        for (int j = 0; j < cntc; ++j) {
            const int s = __shfl(sv, j, 16);
            const float w = dinv[s];
            const uint4 x = *reinterpret_cast<const uint4*>(H + (size_t)s * 128 + c8);
            acc0 = fmaf(w, bflo(x.x), acc0); acc1 = fmaf(w, bfhi(x.x), acc1);
            acc2 = fmaf(w, bflo(x.y), acc2); acc3 = fmaf(w, bfhi(x.y), acc3);
            acc4 = fmaf(w, bflo(x.z), acc4); acc5 = fmaf(w, bfhi(x.z), acc5);
            acc6 = fmaf(w, bflo(x.w), acc6); acc7 = fmaf(w, bfhi(x.w), acc7);
        }
    }

    const float4 b0 = *reinterpret_cast<const float4*>(bias + c8);
    const float4 b1 = *reinterpret_cast<const float4*>(bias + c8 + 4);
    const float r0 = fmaxf(fmaf(acc0, dv, b0.x), 0.f);
    const float r1 = fmaxf(fmaf(acc1, dv, b0.y), 0.f);
    const float r2 = fmaxf(fmaf(acc2, dv, b0.z), 0.f);
    const float r3 = fmaxf(fmaf(acc3, dv, b0.w), 0.f);
    const float r4 = fmaxf(fmaf(acc4, dv, b1.x), 0.f);
    const float r5 = fmaxf(fmaf(acc5, dv, b1.y), 0.f);
    const float r6 = fmaxf(fmaf(acc6, dv, b1.z), 0.f);
    const float r7 = fmaxf(fmaf(acc7, dv, b1.w), 0.f);

    if (OUTBF) {
        uint4 q;
        q.x = pack2(r0, r1); q.y = pack2(r2, r3);
        q.z = pack2(r4, r5); q.w = pack2(r6, r7);
        u16* op = (u16*)outp + (size_t)node * 128 + c8;
        *reinterpret_cast<uint4*>(op) = q;
    } else {
        float* op = (float*)outp + (size_t)node * 128 + c8;
        *reinterpret_cast<float4*>(op)     = make_float4(r0, r1, r2, r3);
        *reinterpret_cast<float4*>(op + 4) = make_float4(r4, r5, r6, r7);
    }
}

// ===========================================================================

extern "C" void kernel_launch(void* const* d_in, const int* in_sizes, int n_in,
                              void* d_out, int out_size, void* d_ws, size_t ws_size,
                              hipStream_t stream) {
    const float* x  = (const float*)d_in[0];
    const int*   ei = (const int*)d_in[1];
    const float* W1 = (const float*)d_in[3];
    const float* b1 = (const float*)d_in[4];
    const float* W2 = (const float*)d_in[5];
    const float* b2 = (const float*)d_in[6];
    float* out = (float*)d_out;

    const int N = in_sizes[0] / 400;
    const int E = in_sizes[1] / 2;
    const int* src = ei;
    const int* dst = ei + E;
    const int NB = (N + 127) >> 7;
    const int KP1 = 448;                // 400 padded to 7*64
    const int KP2 = 128;

    char* ws = (char*)d_ws;
    size_t off = 0;
    auto alloc = [&](size_t bytes) {
        void* p = ws + off;
        off = (off + bytes + 255) & ~(size_t)255;
        return p;
    };
    u32*   bcnt   = (u32*)alloc((size_t)NB * 4);
    u32*   boff   = (u32*)alloc((size_t)(NB + 1) * 4);
    u32*   bcur   = (u32*)alloc((size_t)NB * 4);
    int*   rowptr = (int*)alloc((size_t)(N + 1) * 4);
    float* dinv   = (float*)alloc((size_t)N * 4);
    int*   csr_s  = (int*)alloc((size_t)E * 4);
    u16*   h      = (u16*)alloc((size_t)N * 128 * 2);
    u16*   abf    = (u16*)alloc((size_t)N * 128 * 2);
    int2*  ebuf   = (int2*)alloc((size_t)E * 8);
    u16*   Wt1    = (u16*)alloc((size_t)128 * KP1 * 2);
    u16*   Wt2    = (u16*)alloc((size_t)128 * KP2 * 2);

    const int nb_gm = (N + 127) / 128;
    const int nb_g  = (N + 15) / 16;

    // ---- W prep (tiny) ----
    k_wprep<<<(128 * KP1 + 255) / 256, 256, 0, stream>>>(W1, Wt1, 400, KP1);
    k_wprep<<<(128 * KP2 + 255) / 256, 256, 0, stream>>>(W2, Wt2, 128, KP2);

    // ---- CSR build via bucketed counting sort ----
    k_zero<<<(NB + 255) / 256, 256, 0, stream>>>(bcnt, NB);
    k_bucket_hist<<<HB, 256, 0, stream>>>(dst, bcnt, E, NB);
    k_bucket_scan<<<1, 256, 0, stream>>>(bcnt, boff, bcur, NB, E);
    k_bucket_scatter<<<HB, 256, 0, stream>>>(src, dst, bcur, ebuf, E, NB);
    k_csr_build<<<NB, 256, 0, stream>>>(ebuf, boff, rowptr, dinv, csr_s, N, NB, E);

    // ---- layer 1 ----
    k_gemm_mfma<0><<<nb_gm, 512, 0, stream>>>(x, Wt1, h, N, 400, KP1);
    k_gather<1><<<nb_g, 256, 0, stream>>>(rowptr, csr_s, dinv, h, b1, abf, N);

    // ---- layer 2 ----
    k_gemm_mfma<1><<<nb_gm, 512, 0, stream>>>(abf, Wt2, h, N, 128, KP2);
    k_gather<0><<<nb_g, 256, 0, stream>>>(rowptr, csr_s, dinv, h, b2, out, N);
}